// Round 1
// baseline (38.832 us; speedup 1.0000x reference)
//
#include <hip/hip_runtime.h>
#include <math.h>

typedef float f4 __attribute__((ext_vector_type(4)));

#define NBLOCKS 2048
#define NTHREADS 256

// Kernel 1: streaming accumulation of the 6 second moments of d = pred - targ.
// Each grid-stride iteration handles 4 samples (12 floats = 3 float4 per array).
__global__ __launch_bounds__(NTHREADS) void moments_kernel(
    const f4* __restrict__ pred, const f4* __restrict__ targ,
    float* __restrict__ partials, int ngroups)
{
    float m00 = 0.f, m01 = 0.f, m02 = 0.f, m11 = 0.f, m12 = 0.f, m22 = 0.f;

    const int stride = gridDim.x * blockDim.x;
    for (int g = blockIdx.x * blockDim.x + threadIdx.x; g < ngroups; g += stride) {
        const long long base = 3LL * (long long)g;
        f4 p0 = pred[base + 0], p1 = pred[base + 1], p2 = pred[base + 2];
        f4 t0 = targ[base + 0], t1 = targ[base + 1], t2 = targ[base + 2];
        f4 d0 = p0 - t0, d1 = p1 - t1, d2 = p2 - t2;

        // 4 samples: (d0.x d0.y d0.z) (d0.w d1.x d1.y) (d1.z d1.w d2.x) (d2.y d2.z d2.w)
        float xs[4] = { d0.x, d0.w, d1.z, d2.y };
        float ys[4] = { d0.y, d1.x, d1.w, d2.z };
        float zs[4] = { d0.z, d1.y, d2.x, d2.w };
#pragma unroll
        for (int s = 0; s < 4; ++s) {
            float x = xs[s], y = ys[s], z = zs[s];
            m00 += x * x; m11 += y * y; m22 += z * z;
            m01 += x * y; m02 += x * z; m12 += y * z;
        }
    }

    // Wave-64 butterfly-free down-reduce
    float acc[6] = { m00, m01, m02, m11, m12, m22 };
#pragma unroll
    for (int off = 32; off > 0; off >>= 1) {
#pragma unroll
        for (int k = 0; k < 6; ++k) acc[k] += __shfl_down(acc[k], off, 64);
    }

    __shared__ float sm[4][6];
    const int wave = threadIdx.x >> 6;
    const int lane = threadIdx.x & 63;
    if (lane == 0) {
#pragma unroll
        for (int k = 0; k < 6; ++k) sm[wave][k] = acc[k];
    }
    __syncthreads();
    if (threadIdx.x == 0) {
#pragma unroll
        for (int k = 0; k < 6; ++k)
            partials[blockIdx.x * 6 + k] = sm[0][k] + sm[1][k] + sm[2][k] + sm[3][k];
    }
}

// Kernel 2: reduce block partials (double), add scalar tail, 3x3 inverse +
// logdet in double, write |logdet + quad| as float.
__global__ __launch_bounds__(NTHREADS) void finalize_kernel(
    const float* __restrict__ partials, const float* __restrict__ sigma,
    const float* __restrict__ pred, const float* __restrict__ targ,
    float* __restrict__ out, int nblocks, int tail_start, int n)
{
    double a[6] = { 0, 0, 0, 0, 0, 0 };
    for (int b = threadIdx.x; b < nblocks; b += blockDim.x) {
#pragma unroll
        for (int k = 0; k < 6; ++k) a[k] += (double)partials[b * 6 + k];
    }
#pragma unroll
    for (int off = 32; off > 0; off >>= 1) {
#pragma unroll
        for (int k = 0; k < 6; ++k) a[k] += __shfl_down(a[k], off, 64);
    }

    __shared__ double sm[4][6];
    const int wave = threadIdx.x >> 6;
    const int lane = threadIdx.x & 63;
    if (lane == 0) {
#pragma unroll
        for (int k = 0; k < 6; ++k) sm[wave][k] = a[k];
    }
    __syncthreads();

    if (threadIdx.x == 0) {
        double M[6];
#pragma unroll
        for (int k = 0; k < 6; ++k) M[k] = sm[0][k] + sm[1][k] + sm[2][k] + sm[3][k];

        // scalar tail (samples not covered by the float4 groups)
        for (int i = tail_start; i < n; ++i) {
            double x = (double)pred[3 * i + 0] - (double)targ[3 * i + 0];
            double y = (double)pred[3 * i + 1] - (double)targ[3 * i + 1];
            double z = (double)pred[3 * i + 2] - (double)targ[3 * i + 2];
            M[0] += x * x; M[1] += x * y; M[2] += x * z;
            M[3] += y * y; M[4] += y * z; M[5] += z * z;
        }

        const double invN = 1.0 / (double)n;
#pragma unroll
        for (int k = 0; k < 6; ++k) M[k] *= invN;

        // general 3x3 inverse via adjugate (double)
        double s00 = sigma[0], s01 = sigma[1], s02 = sigma[2];
        double s10 = sigma[3], s11 = sigma[4], s12 = sigma[5];
        double s20 = sigma[6], s21 = sigma[7], s22 = sigma[8];

        double c00 = s11 * s22 - s12 * s21;
        double c01 = s12 * s20 - s10 * s22;
        double c02 = s10 * s21 - s11 * s20;
        double det = s00 * c00 + s01 * c01 + s02 * c02;
        double invdet = 1.0 / det;

        double i00 = (s11 * s22 - s12 * s21) * invdet;
        double i01 = (s02 * s21 - s01 * s22) * invdet;
        double i02 = (s01 * s12 - s02 * s11) * invdet;
        double i10 = (s12 * s20 - s10 * s22) * invdet;
        double i11 = (s00 * s22 - s02 * s20) * invdet;
        double i12 = (s02 * s10 - s00 * s12) * invdet;
        double i20 = (s10 * s21 - s11 * s20) * invdet;
        double i21 = (s01 * s20 - s00 * s21) * invdet;
        double i22 = (s00 * s11 - s01 * s10) * invdet;

        // quad = sum_ij inv_ij * mean(d_i d_j); M = [m00,m01,m02,m11,m12,m22]
        double quad = i00 * M[0] + i11 * M[3] + i22 * M[5]
                    + (i01 + i10) * M[1] + (i02 + i20) * M[2] + (i12 + i21) * M[4];

        double logdet = log(fabs(det));
        out[0] = (float)fabs(logdet + quad);
    }
}

extern "C" void kernel_launch(void* const* d_in, const int* in_sizes, int n_in,
                              void* d_out, int out_size, void* d_ws, size_t ws_size,
                              hipStream_t stream) {
    const float* pred  = (const float*)d_in[0];
    const float* targ  = (const float*)d_in[1];
    const float* sigma = (const float*)d_in[2];
    float* out = (float*)d_out;

    const int n = in_sizes[0] / 3;        // number of samples
    const int ngroups = n / 4;            // 4 samples per float4-group
    const int tail_start = ngroups * 4;

    float* partials = (float*)d_ws;       // NBLOCKS * 6 floats

    moments_kernel<<<NBLOCKS, NTHREADS, 0, stream>>>(
        (const f4*)pred, (const f4*)targ, partials, ngroups);
    finalize_kernel<<<1, NTHREADS, 0, stream>>>(
        partials, sigma, pred, targ, out, NBLOCKS, tail_start, n);
}